// Round 1
// baseline (314.086 us; speedup 1.0000x reference)
//
#include <hip/hip_runtime.h>

typedef unsigned short ushort_t;
typedef __attribute__((ext_vector_type(8))) __bf16 bf16x8;
typedef __attribute__((ext_vector_type(4))) float f32x4;
typedef __attribute__((ext_vector_type(4))) ushort_t ushort4_t;

__device__ inline ushort_t f2bf(float f){
  union { float f; unsigned u; } v; v.f = f;
  unsigned r = v.u + 0x7FFFu + ((v.u >> 16) & 1u);
  return (ushort_t)(r >> 16);
}

__device__ inline f32x4 mfma16(bf16x8 a, bf16x8 b, f32x4 c){
  return __builtin_amdgcn_mfma_f32_16x16x32_bf16(a, b, c, 0, 0, 0);
}

__device__ inline float rmax16(float v){
  v = fmaxf(v, __shfl_xor(v, 1));
  v = fmaxf(v, __shfl_xor(v, 2));
  v = fmaxf(v, __shfl_xor(v, 4));
  v = fmaxf(v, __shfl_xor(v, 8));
  return v;
}
__device__ inline float rsum16(float v){
  v += __shfl_xor(v, 1);
  v += __shfl_xor(v, 2);
  v += __shfl_xor(v, 4);
  v += __shfl_xor(v, 8);
  return v;
}

// ---------------- Kernel A1: spectral norm sigma (one block per weight) ----
__global__ void sigma_kernel(const float* __restrict__ Wf, const float* __restrict__ uf,
                             const float* __restrict__ Wg, const float* __restrict__ ug,
                             const float* __restrict__ Wh, const float* __restrict__ uh,
                             const float* __restrict__ Wc, const float* __restrict__ uc,
                             float* __restrict__ inv_sigma){
  int w = blockIdx.x, t = threadIdx.x;
  const float *W, *u; int Cout;
  if      (w == 0){ W = Wf; u = uf; Cout = 32; }
  else if (w == 1){ W = Wg; u = ug; Cout = 32; }
  else if (w == 2){ W = Wh; u = uh; Cout = 256; }
  else            { W = Wc; u = uc; Cout = 256; }
  __shared__ float su[256], sv[256], red[256];
  su[t] = u[t];
  __syncthreads();
  float v = 0.f;
  if (t < Cout){
    for (int i = 0; i < 256; ++i) v += W[i*Cout + t] * su[i];
  }
  red[t] = (t < Cout) ? v*v : 0.f;
  __syncthreads();
  for (int s = 128; s > 0; s >>= 1){ if (t < s) red[t] += red[t+s]; __syncthreads(); }
  float nv = sqrtf(red[0]) + 1e-12f;
  __syncthreads();
  if (t < Cout) sv[t] = v / nv;
  __syncthreads();
  float wv = 0.f;
  for (int d = 0; d < Cout; ++d) wv += W[t*Cout + d] * sv[d];
  __syncthreads();
  red[t] = wv * wv;
  __syncthreads();
  for (int s = 128; s > 0; s >>= 1){ if (t < s) red[t] += red[t+s]; __syncthreads(); }
  if (t == 0){
    float ss2 = red[0];
    float sig = ss2 / (sqrtf(ss2) + 1e-12f);   // sigma = u_new . (W v)
    inv_sigma[w] = 1.0f / sig;
  }
}

// ---------------- Kernel A2: transpose + 1/sigma fold + bf16 cast ----------
__global__ void prep_weights(const float* __restrict__ Wf, const float* __restrict__ Wg,
                             const float* __restrict__ Wh, const float* __restrict__ Wc,
                             const float* __restrict__ inv_sigma,
                             ushort_t* __restrict__ WallT, ushort_t* __restrict__ WcT){
  int idx = blockIdx.x * 256 + threadIdx.x;   // 0 .. 147455
  if (idx < 81920){                            // WallT[c][k], c in [0,320)
    int c = idx >> 8, k = idx & 255;
    float val, is;
    if (c < 32)      { val = Wf[k*32  + c      ]; is = inv_sigma[0]; }
    else if (c < 64) { val = Wg[k*32  + (c-32) ]; is = inv_sigma[1]; }
    else             { val = Wh[k*256 + (c-64) ]; is = inv_sigma[2]; }
    WallT[idx] = f2bf(val * is);
  } else {
    int j = idx - 81920; int c = j >> 8, k = j & 255;
    WcT[j] = f2bf(Wc[k*256 + c] * inv_sigma[3]);
  }
}

// ---------------- Kernel B: f,g,h = x @ [Wf|Wg|Wh]_sn + bias ---------------
// 4 waves/block, 16 rows/wave, 20 col-tiles (f:0-1, g:2-3, h:4-19), K=256.
__global__ __launch_bounds__(256) void fgh_kernel(
    const float* __restrict__ x, const ushort_t* __restrict__ WallT,
    const float* __restrict__ bf, const float* __restrict__ bg, const float* __restrict__ bh,
    ushort_t* __restrict__ fO, ushort_t* __restrict__ gO, ushort_t* __restrict__ hT){
  int t = threadIdx.x;
  int wv = t >> 6, l = t & 63, lrow = l & 15, lgrp = l >> 4;
  long r0 = (long)blockIdx.x * 64 + wv * 16;
  const float* xrow = x + (r0 + lrow) * 256;
  f32x4 acc[20];
#pragma unroll
  for (int i = 0; i < 20; ++i) acc[i] = f32x4{0.f,0.f,0.f,0.f};
#pragma unroll
  for (int ks = 0; ks < 8; ++ks){
    int kk = ks*32 + lgrp*8;
    f32x4 xa = *(const f32x4*)(xrow + kk);
    f32x4 xb = *(const f32x4*)(xrow + kk + 4);
    union { ushort_t u[8]; bf16x8 v; } A;
#pragma unroll
    for (int j = 0; j < 4; ++j){ A.u[j] = f2bf(xa[j]); A.u[4+j] = f2bf(xb[j]); }
#pragma unroll
    for (int ct = 0; ct < 20; ++ct){
      bf16x8 bb = *(const bf16x8*)(WallT + (ct*16 + lrow)*256 + kk);
      acc[ct] = mfma16(A.v, bb, acc[ct]);
    }
  }
#pragma unroll
  for (int ct = 0; ct < 20; ++ct){
    int col = ct*16 + lrow;
    long rowb = r0 + lgrp*4;
    if (col < 32){
      float bv = bf[col];
#pragma unroll
      for (int rg = 0; rg < 4; ++rg) fO[(rowb+rg)*32 + col] = f2bf(acc[ct][rg] + bv);
    } else if (col < 64){
      float bv = bg[col-32];
#pragma unroll
      for (int rg = 0; rg < 4; ++rg) gO[(rowb+rg)*32 + (col-32)] = f2bf(acc[ct][rg] + bv);
    } else {
      int hc = col - 64;
      float bv = bh[hc];
      long bb = rowb >> 12, n = rowb & 4095;
      ushort4_t pk;
#pragma unroll
      for (int rg = 0; rg < 4; ++rg) pk[rg] = f2bf(acc[ct][rg] + bv);
      *(ushort4_t*)(hT + (bb*256 + hc)*4096 + n) = pk;   // h transposed [b][c][n]
    }
  }
}

// ---------------- Kernel C: flash attention ---------------------------------
// grid 512: batch = bid&7 (XCD-pins per-batch KV in one L2), qtile = bid>>3.
// 4 waves x 16 q-rows; KV tile 64; QK^T direct-layout MFMA; P via wave-private
// padded LDS; V reg-staged global->LDS (issue-early), shared across waves.
__global__ __launch_bounds__(256) void attn_kernel(
    const ushort_t* __restrict__ fI, const ushort_t* __restrict__ gI,
    const ushort_t* __restrict__ hT, ushort_t* __restrict__ O){
  __shared__ ushort_t ldsV[256*72];      // [col][key] stride 72 (pad vs 64)
  __shared__ ushort_t ldsP[4][16*72];    // per-wave P: [qrow][key] stride 72
  int bid = blockIdx.x, t = threadIdx.x;
  int b = bid & 7, qt = bid >> 3;
  int wv = t >> 6, l = t & 63, lrow = l & 15, lgrp = l >> 4;
  int q0 = qt*64 + wv*16;
  bf16x8 qa = *(const bf16x8*)(gI + ((long)b*4096 + q0 + lrow)*32 + lgrp*8);
  const ushort_t* fB = fI + (long)b*4096*32;
  const ushort_t* hB = hT + (long)b*256*4096;
  f32x4 o[16];
#pragma unroll
  for (int i = 0; i < 16; ++i) o[i] = f32x4{0.f,0.f,0.f,0.f};
  float m[4]  = {-1e30f,-1e30f,-1e30f,-1e30f};
  float li[4] = {0.f,0.f,0.f,0.f};
  int vcol = t >> 3;          // 0..31
  int vko  = (t & 7) * 8;     // 0..56
  ushort_t* Pw = ldsP[wv];
  for (int kt = 0; kt < 64; ++kt){
    int key0 = kt * 64;
    __syncthreads();                       // prev tile's LDS reads done
    bf16x8 vreg[8];                        // issue V loads early (hide HBM/L2)
#pragma unroll
    for (int i = 0; i < 8; ++i)
      vreg[i] = *(const bf16x8*)(hB + (long)(i*32 + vcol)*4096 + key0 + vko);
    // S = Q K^T  (16 q-rows x 64 keys)
    f32x4 s[4];
#pragma unroll
    for (int st = 0; st < 4; ++st){
      bf16x8 kb = *(const bf16x8*)(fB + (key0 + st*16 + lrow)*32 + lgrp*8);
      s[st] = mfma16(qa, kb, f32x4{0.f,0.f,0.f,0.f});
    }
    // online softmax (rows live in 16-lane groups, reg = row%4)
    float mn[4], sc[4];
#pragma unroll
    for (int rg = 0; rg < 4; ++rg){
      float tm = fmaxf(fmaxf(s[0][rg], s[1][rg]), fmaxf(s[2][rg], s[3][rg]));
      tm = rmax16(tm);
      mn[rg] = fmaxf(m[rg], tm);
      sc[rg] = __expf(m[rg] - mn[rg]);
      m[rg]  = mn[rg];
    }
    float rs[4] = {0.f,0.f,0.f,0.f};
#pragma unroll
    for (int st = 0; st < 4; ++st)
#pragma unroll
      for (int rg = 0; rg < 4; ++rg){
        float pv = __expf(s[st][rg] - mn[rg]);
        s[st][rg] = pv;
        rs[rg] += pv;
      }
#pragma unroll
    for (int rg = 0; rg < 4; ++rg) li[rg] = li[rg]*sc[rg] + rsum16(rs[rg]);
#pragma unroll
    for (int ct = 0; ct < 16; ++ct)
#pragma unroll
      for (int rg = 0; rg < 4; ++rg) o[ct][rg] *= sc[rg];
    // P -> LDS (D-layout scatter), re-read as A-fragments
#pragma unroll
    for (int st = 0; st < 4; ++st)
#pragma unroll
      for (int rg = 0; rg < 4; ++rg)
        Pw[(lgrp*4 + rg)*72 + st*16 + lrow] = f2bf(s[st][rg]);
    asm volatile("s_waitcnt lgkmcnt(0)" ::: "memory");
    bf16x8 pa0 = *(const bf16x8*)(Pw + lrow*72 + lgrp*8);
    bf16x8 pa1 = *(const bf16x8*)(Pw + lrow*72 + 32 + lgrp*8);
    // V regs -> LDS, then block-wide consume
#pragma unroll
    for (int i = 0; i < 8; ++i)
      *(bf16x8*)(ldsV + (i*32 + vcol)*72 + vko) = vreg[i];
    __syncthreads();
#pragma unroll
    for (int ct = 0; ct < 16; ++ct){
      const ushort_t* vb = ldsV + (ct*16 + lrow)*72 + lgrp*8;
      bf16x8 b0 = *(const bf16x8*)vb;
      bf16x8 b1 = *(const bf16x8*)(vb + 32);
      o[ct] = mfma16(pa0, b0, o[ct]);
      o[ct] = mfma16(pa1, b1, o[ct]);
    }
  }
  ushort_t* Ob = O + ((long)b*4096 + q0)*256;
#pragma unroll
  for (int ct = 0; ct < 16; ++ct){
    int col = ct*16 + lrow;
#pragma unroll
    for (int rg = 0; rg < 4; ++rg){
      int row = lgrp*4 + rg;
      Ob[(long)row*256 + col] = f2bf(o[ct][rg] / li[rg]);
    }
  }
}

// ---------------- Kernel D: out = gamma*(O @ Wc_sn + bc) + x ---------------
__global__ __launch_bounds__(256) void out_kernel(
    const ushort_t* __restrict__ O, const ushort_t* __restrict__ WcT,
    const float* __restrict__ bc, const float* __restrict__ x,
    const float* __restrict__ gamma, float* __restrict__ out){
  int t = threadIdx.x;
  int wv = t >> 6, l = t & 63, lrow = l & 15, lgrp = l >> 4;
  long r0 = (long)blockIdx.x * 64 + wv * 16;
  f32x4 acc[16];
#pragma unroll
  for (int i = 0; i < 16; ++i) acc[i] = f32x4{0.f,0.f,0.f,0.f};
#pragma unroll
  for (int ks = 0; ks < 8; ++ks){
    int kk = ks*32 + lgrp*8;
    bf16x8 a = *(const bf16x8*)(O + (r0 + lrow)*256 + kk);
#pragma unroll
    for (int ct = 0; ct < 16; ++ct){
      bf16x8 bb = *(const bf16x8*)(WcT + (ct*16 + lrow)*256 + kk);
      acc[ct] = mfma16(a, bb, acc[ct]);
    }
  }
  float gm = gamma[0];
#pragma unroll
  for (int ct = 0; ct < 16; ++ct){
    int col = ct*16 + lrow;
    float bv = bc[col];
#pragma unroll
    for (int rg = 0; rg < 4; ++rg){
      long row = r0 + lgrp*4 + rg;
      out[row*256 + col] = gm*(acc[ct][rg] + bv) + x[row*256 + col];
    }
  }
}

extern "C" void kernel_launch(void* const* d_in, const int* in_sizes, int n_in,
                              void* d_out, int out_size, void* d_ws, size_t ws_size,
                              hipStream_t stream){
  (void)in_sizes; (void)n_in; (void)out_size; (void)ws_size;
  const float* x  = (const float*)d_in[0];
  const float* Wf = (const float*)d_in[1];
  const float* bf = (const float*)d_in[2];
  const float* uf = (const float*)d_in[3];
  const float* Wg = (const float*)d_in[4];
  const float* bg = (const float*)d_in[5];
  const float* ug = (const float*)d_in[6];
  const float* Wh = (const float*)d_in[7];
  const float* bh = (const float*)d_in[8];
  const float* uh = (const float*)d_in[9];
  const float* Wc = (const float*)d_in[10];
  const float* bc = (const float*)d_in[11];
  const float* uc = (const float*)d_in[12];
  const float* gamma = (const float*)d_in[13];
  float* out = (float*)d_out;

  char* w = (char*)d_ws;
  float*    inv_sigma = (float*)w;                                 // 16 B (pad 256)
  ushort_t* WallT = (ushort_t*)(w + 256);                          // 320*256*2 = 163840
  ushort_t* WcT   = (ushort_t*)(w + 256 + 163840);                 // 256*256*2 = 131072
  ushort_t* fW    = (ushort_t*)(w + 295168);                       // 8*4096*32*2 = 2097152
  ushort_t* gW    = (ushort_t*)(w + 295168 + 2097152);             // 2097152
  ushort_t* hTW   = (ushort_t*)(w + 295168 + 2*2097152);           // 8*256*4096*2 = 16777216
  ushort_t* OW    = (ushort_t*)(w + 295168 + 2*2097152 + 16777216);// 16777216

  hipLaunchKernelGGL(sigma_kernel, dim3(4),   dim3(256), 0, stream,
                     Wf, uf, Wg, ug, Wh, uh, Wc, uc, inv_sigma);
  hipLaunchKernelGGL(prep_weights, dim3(576), dim3(256), 0, stream,
                     Wf, Wg, Wh, Wc, inv_sigma, WallT, WcT);
  hipLaunchKernelGGL(fgh_kernel,   dim3(512), dim3(256), 0, stream,
                     x, WallT, bf, bg, bh, fW, gW, hTW);
  hipLaunchKernelGGL(attn_kernel,  dim3(512), dim3(256), 0, stream,
                     fW, gW, hTW, OW);
  hipLaunchKernelGGL(out_kernel,   dim3(512), dim3(256), 0, stream,
                     OW, WcT, bc, x, gamma, out);
}

// Round 2
// 293.270 us; speedup vs baseline: 1.0710x; 1.0710x over previous
//
#include <hip/hip_runtime.h>

typedef unsigned short ushort_t;
typedef __attribute__((ext_vector_type(8))) __bf16 bf16x8;
typedef __attribute__((ext_vector_type(4))) float f32x4;
typedef __attribute__((ext_vector_type(4))) ushort_t ushort4_t;

__device__ inline ushort_t f2bf(float f){           // compiler emits v_cvt_pk_bf16_f32
  __bf16 h = (__bf16)f;
  union { __bf16 h; ushort_t u; } v; v.h = h;
  return v.u;
}

__device__ inline f32x4 mfma16(bf16x8 a, bf16x8 b, f32x4 c){
  return __builtin_amdgcn_mfma_f32_16x16x32_bf16(a, b, c, 0, 0, 0);
}

__device__ inline float rmax16(float v){
  v = fmaxf(v, __shfl_xor(v, 1));
  v = fmaxf(v, __shfl_xor(v, 2));
  v = fmaxf(v, __shfl_xor(v, 4));
  v = fmaxf(v, __shfl_xor(v, 8));
  return v;
}
__device__ inline float rsum16(float v){
  v += __shfl_xor(v, 1);
  v += __shfl_xor(v, 2);
  v += __shfl_xor(v, 4);
  v += __shfl_xor(v, 8);
  return v;
}

// ---------------- Kernel A1: spectral norm sigma (one block per weight) ----
__global__ void sigma_kernel(const float* __restrict__ Wf, const float* __restrict__ uf,
                             const float* __restrict__ Wg, const float* __restrict__ ug,
                             const float* __restrict__ Wh, const float* __restrict__ uh,
                             const float* __restrict__ Wc, const float* __restrict__ uc,
                             float* __restrict__ inv_sigma){
  int w = blockIdx.x, t = threadIdx.x;
  const float *W, *u; int Cout;
  if      (w == 0){ W = Wf; u = uf; Cout = 32; }
  else if (w == 1){ W = Wg; u = ug; Cout = 32; }
  else if (w == 2){ W = Wh; u = uh; Cout = 256; }
  else            { W = Wc; u = uc; Cout = 256; }
  __shared__ float su[256], sv[256], red[256];
  su[t] = u[t];
  __syncthreads();
  float v = 0.f;
  if (t < Cout){
    for (int i = 0; i < 256; ++i) v += W[i*Cout + t] * su[i];
  }
  red[t] = (t < Cout) ? v*v : 0.f;
  __syncthreads();
  for (int s = 128; s > 0; s >>= 1){ if (t < s) red[t] += red[t+s]; __syncthreads(); }
  float nv = sqrtf(red[0]) + 1e-12f;
  __syncthreads();
  if (t < Cout) sv[t] = v / nv;
  __syncthreads();
  float wv = 0.f;
  for (int d = 0; d < Cout; ++d) wv += W[t*Cout + d] * sv[d];
  __syncthreads();
  red[t] = wv * wv;
  __syncthreads();
  for (int s = 128; s > 0; s >>= 1){ if (t < s) red[t] += red[t+s]; __syncthreads(); }
  if (t == 0){
    float ss2 = red[0];
    float sig = ss2 / (sqrtf(ss2) + 1e-12f);   // sigma = u_new . (W v)
    inv_sigma[w] = 1.0f / sig;
  }
}

// ---------------- Kernel A2: transpose + 1/sigma fold + bf16 cast ----------
__global__ void prep_weights(const float* __restrict__ Wf, const float* __restrict__ Wg,
                             const float* __restrict__ Wh, const float* __restrict__ Wc,
                             const float* __restrict__ inv_sigma,
                             ushort_t* __restrict__ WallT, ushort_t* __restrict__ WcT){
  int idx = blockIdx.x * 256 + threadIdx.x;   // 0 .. 147455
  if (idx < 81920){                            // WallT[c][k], c in [0,320)
    int c = idx >> 8, k = idx & 255;
    float val, is;
    if (c < 32)      { val = Wf[k*32  + c      ]; is = inv_sigma[0]; }
    else if (c < 64) { val = Wg[k*32  + (c-32) ]; is = inv_sigma[1]; }
    else             { val = Wh[k*256 + (c-64) ]; is = inv_sigma[2]; }
    WallT[idx] = f2bf(val * is);
  } else {
    int j = idx - 81920; int c = j >> 8, k = j & 255;
    WcT[j] = f2bf(Wc[k*256 + c] * inv_sigma[3]);
  }
}

// ---------------- Kernel B: f,g,h = x @ [Wf|Wg|Wh]_sn + bias ---------------
// 4 waves/block, 16 rows/wave, 20 col-tiles (f:0-1, g:2-3, h:4-19), K=256.
__global__ __launch_bounds__(256) void fgh_kernel(
    const float* __restrict__ x, const ushort_t* __restrict__ WallT,
    const float* __restrict__ bf, const float* __restrict__ bg, const float* __restrict__ bh,
    ushort_t* __restrict__ fO, ushort_t* __restrict__ gO, ushort_t* __restrict__ hT){
  int t = threadIdx.x;
  int wv = t >> 6, l = t & 63, lrow = l & 15, lgrp = l >> 4;
  long r0 = (long)blockIdx.x * 64 + wv * 16;
  const float* xrow = x + (r0 + lrow) * 256;
  f32x4 acc[20];
#pragma unroll
  for (int i = 0; i < 20; ++i) acc[i] = f32x4{0.f,0.f,0.f,0.f};
#pragma unroll
  for (int ks = 0; ks < 8; ++ks){
    int kk = ks*32 + lgrp*8;
    f32x4 xa = *(const f32x4*)(xrow + kk);
    f32x4 xb = *(const f32x4*)(xrow + kk + 4);
    union { __bf16 h[8]; bf16x8 v; } A;
#pragma unroll
    for (int j = 0; j < 4; ++j){ A.h[j] = (__bf16)xa[j]; A.h[4+j] = (__bf16)xb[j]; }
#pragma unroll
    for (int ct = 0; ct < 20; ++ct){
      bf16x8 bb = *(const bf16x8*)(WallT + (ct*16 + lrow)*256 + kk);
      acc[ct] = mfma16(A.v, bb, acc[ct]);
    }
  }
#pragma unroll
  for (int ct = 0; ct < 20; ++ct){
    int col = ct*16 + lrow;
    long rowb = r0 + lgrp*4;
    if (col < 32){
      float bv = bf[col];
#pragma unroll
      for (int rg = 0; rg < 4; ++rg) fO[(rowb+rg)*32 + col] = f2bf(acc[ct][rg] + bv);
    } else if (col < 64){
      float bv = bg[col-32];
#pragma unroll
      for (int rg = 0; rg < 4; ++rg) gO[(rowb+rg)*32 + (col-32)] = f2bf(acc[ct][rg] + bv);
    } else {
      int hc = col - 64;
      float bv = bh[hc];
      long bb = rowb >> 12, n = rowb & 4095;
      ushort4_t pk;
#pragma unroll
      for (int rg = 0; rg < 4; ++rg) pk[rg] = f2bf(acc[ct][rg] + bv);
      *(ushort4_t*)(hT + (bb*256 + hc)*4096 + n) = pk;   // h transposed [b][c][n]
    }
  }
}

// ---------------- Kernel C: flash attention ---------------------------------
// grid 512: batch = bid&7 (XCD-pins per-batch KV in one L2), qtile = bid>>3.
// 4 waves x 16 q-rows; KV tile 64; QK^T direct-layout MFMA; P via wave-private
// padded LDS; V reg-staged global->LDS (issue-early); defer-max (T13, THR=8);
// s_setprio around PV MFMAs (T5).
__global__ __launch_bounds__(256) void attn_kernel(
    const ushort_t* __restrict__ fI, const ushort_t* __restrict__ gI,
    const ushort_t* __restrict__ hT, ushort_t* __restrict__ O){
  __shared__ ushort_t ldsV[256*72];      // [col][key] stride 72 (pad vs 64)
  __shared__ ushort_t ldsP[4][16*72];    // per-wave P: [qrow][key] stride 72
  int bid = blockIdx.x, t = threadIdx.x;
  int b = bid & 7, qt = bid >> 3;
  int wv = t >> 6, l = t & 63, lrow = l & 15, lgrp = l >> 4;
  int q0 = qt*64 + wv*16;
  bf16x8 qa = *(const bf16x8*)(gI + ((long)b*4096 + q0 + lrow)*32 + lgrp*8);
  const ushort_t* hB = hT + (long)b*256*4096;
  f32x4 o[16];
#pragma unroll
  for (int i = 0; i < 16; ++i) o[i] = f32x4{0.f,0.f,0.f,0.f};
  float m[4]  = {-1e30f,-1e30f,-1e30f,-1e30f};
  float li[4] = {0.f,0.f,0.f,0.f};
  int vcol = t >> 3;          // 0..31
  int vko  = (t & 7) * 8;     // 0..56
  ushort_t* Pw = ldsP[wv];
  // persistent pointers: V-staging rows and K fragment base (advance per tile)
  const ushort_t* vp[8];
#pragma unroll
  for (int i = 0; i < 8; ++i) vp[i] = hB + (long)(i*32 + vcol)*4096 + vko;
  const ushort_t* kp = fI + (long)b*4096*32 + lrow*32 + lgrp*8;
  for (int kt = 0; kt < 64; ++kt){
    bf16x8 vreg[8];                        // issue V loads before barrier
#pragma unroll
    for (int i = 0; i < 8; ++i){ vreg[i] = *(const bf16x8*)vp[i]; vp[i] += 64; }
    __syncthreads();                       // prev tile's ldsV reads done
    // S = Q K^T  (16 q-rows x 64 keys); K tiles at imm offsets 0/1024/2048/3072 B
    f32x4 s[4];
#pragma unroll
    for (int st = 0; st < 4; ++st){
      bf16x8 kb = *(const bf16x8*)(kp + st*512);
      s[st] = mfma16(qa, kb, f32x4{0.f,0.f,0.f,0.f});
    }
    kp += 2048;
    // row maxima (rows live in 16-lane groups, reg = row%4)
    float tm[4];
    int viol = 0;
#pragma unroll
    for (int rg = 0; rg < 4; ++rg){
      float v0 = fmaxf(fmaxf(s[0][rg], s[1][rg]), fmaxf(s[2][rg], s[3][rg]));
      tm[rg] = rmax16(v0);
      viol |= (tm[rg] > m[rg] + 8.f) ? 1 : 0;
    }
    if (__any(viol)){                      // defer-max: rescale only on growth
      float sc[4];
#pragma unroll
      for (int rg = 0; rg < 4; ++rg){
        float mn = fmaxf(m[rg], tm[rg]);
        sc[rg] = __expf(m[rg] - mn);
        m[rg]  = mn;
        li[rg] *= sc[rg];
      }
#pragma unroll
      for (int ct = 0; ct < 16; ++ct)
#pragma unroll
        for (int rg = 0; rg < 4; ++rg) o[ct][rg] *= sc[rg];
    }
    // P = exp(s - m), pack to LDS (D-layout scatter), accumulate row sums
    float rs[4] = {0.f,0.f,0.f,0.f};
#pragma unroll
    for (int st = 0; st < 4; ++st)
#pragma unroll
      for (int rg = 0; rg < 4; ++rg){
        float pv = __expf(s[st][rg] - m[rg]);
        rs[rg] += pv;
        Pw[(lgrp*4 + rg)*72 + st*16 + lrow] = f2bf(pv);
      }
#pragma unroll
    for (int rg = 0; rg < 4; ++rg) li[rg] += rsum16(rs[rg]);
    asm volatile("s_waitcnt lgkmcnt(0)" ::: "memory");
    bf16x8 pa0 = *(const bf16x8*)(Pw + lrow*72 + lgrp*8);
    bf16x8 pa1 = *(const bf16x8*)(Pw + lrow*72 + 32 + lgrp*8);
    // V regs -> LDS, then block-wide consume
#pragma unroll
    for (int i = 0; i < 8; ++i)
      *(bf16x8*)(ldsV + (i*32 + vcol)*72 + vko) = vreg[i];
    __syncthreads();
    __builtin_amdgcn_s_setprio(1);
#pragma unroll
    for (int ct = 0; ct < 16; ++ct){
      const ushort_t* vb = ldsV + (ct*16 + lrow)*72 + lgrp*8;
      bf16x8 b0 = *(const bf16x8*)vb;
      bf16x8 b1 = *(const bf16x8*)(vb + 32);
      o[ct] = mfma16(pa0, b0, o[ct]);
      o[ct] = mfma16(pa1, b1, o[ct]);
    }
    __builtin_amdgcn_s_setprio(0);
  }
  ushort_t* Ob = O + ((long)b*4096 + q0)*256;
#pragma unroll
  for (int ct = 0; ct < 16; ++ct){
    int col = ct*16 + lrow;
#pragma unroll
    for (int rg = 0; rg < 4; ++rg){
      int row = lgrp*4 + rg;
      Ob[(long)row*256 + col] = f2bf(o[ct][rg] / li[rg]);
    }
  }
}

// ---------------- Kernel D: out = gamma*(O @ Wc_sn + bc) + x ---------------
__global__ __launch_bounds__(256) void out_kernel(
    const ushort_t* __restrict__ O, const ushort_t* __restrict__ WcT,
    const float* __restrict__ bc, const float* __restrict__ x,
    const float* __restrict__ gamma, float* __restrict__ out){
  int t = threadIdx.x;
  int wv = t >> 6, l = t & 63, lrow = l & 15, lgrp = l >> 4;
  long r0 = (long)blockIdx.x * 64 + wv * 16;
  f32x4 acc[16];
#pragma unroll
  for (int i = 0; i < 16; ++i) acc[i] = f32x4{0.f,0.f,0.f,0.f};
#pragma unroll
  for (int ks = 0; ks < 8; ++ks){
    int kk = ks*32 + lgrp*8;
    bf16x8 a = *(const bf16x8*)(O + (r0 + lrow)*256 + kk);
#pragma unroll
    for (int ct = 0; ct < 16; ++ct){
      bf16x8 bb = *(const bf16x8*)(WcT + (ct*16 + lrow)*256 + kk);
      acc[ct] = mfma16(a, bb, acc[ct]);
    }
  }
  float gm = gamma[0];
#pragma unroll
  for (int ct = 0; ct < 16; ++ct){
    int col = ct*16 + lrow;
    float bv = bc[col];
#pragma unroll
    for (int rg = 0; rg < 4; ++rg){
      long row = r0 + lgrp*4 + rg;
      out[row*256 + col] = gm*(acc[ct][rg] + bv) + x[row*256 + col];
    }
  }
}

extern "C" void kernel_launch(void* const* d_in, const int* in_sizes, int n_in,
                              void* d_out, int out_size, void* d_ws, size_t ws_size,
                              hipStream_t stream){
  (void)in_sizes; (void)n_in; (void)out_size; (void)ws_size;
  const float* x  = (const float*)d_in[0];
  const float* Wf = (const float*)d_in[1];
  const float* bf = (const float*)d_in[2];
  const float* uf = (const float*)d_in[3];
  const float* Wg = (const float*)d_in[4];
  const float* bg = (const float*)d_in[5];
  const float* ug = (const float*)d_in[6];
  const float* Wh = (const float*)d_in[7];
  const float* bh = (const float*)d_in[8];
  const float* uh = (const float*)d_in[9];
  const float* Wc = (const float*)d_in[10];
  const float* bc = (const float*)d_in[11];
  const float* uc = (const float*)d_in[12];
  const float* gamma = (const float*)d_in[13];
  float* out = (float*)d_out;

  char* w = (char*)d_ws;
  float*    inv_sigma = (float*)w;                                 // 16 B (pad 256)
  ushort_t* WallT = (ushort_t*)(w + 256);                          // 320*256*2 = 163840
  ushort_t* WcT   = (ushort_t*)(w + 256 + 163840);                 // 256*256*2 = 131072
  ushort_t* fW    = (ushort_t*)(w + 295168);                       // 8*4096*32*2 = 2097152
  ushort_t* gW    = (ushort_t*)(w + 295168 + 2097152);             // 2097152
  ushort_t* hTW   = (ushort_t*)(w + 295168 + 2*2097152);           // 8*256*4096*2 = 16777216
  ushort_t* OW    = (ushort_t*)(w + 295168 + 2*2097152 + 16777216);// 16777216

  hipLaunchKernelGGL(sigma_kernel, dim3(4),   dim3(256), 0, stream,
                     Wf, uf, Wg, ug, Wh, uh, Wc, uc, inv_sigma);
  hipLaunchKernelGGL(prep_weights, dim3(576), dim3(256), 0, stream,
                     Wf, Wg, Wh, Wc, inv_sigma, WallT, WcT);
  hipLaunchKernelGGL(fgh_kernel,   dim3(512), dim3(256), 0, stream,
                     x, WallT, bf, bg, bh, fW, gW, hTW);
  hipLaunchKernelGGL(attn_kernel,  dim3(512), dim3(256), 0, stream,
                     fW, gW, hTW, OW);
  hipLaunchKernelGGL(out_kernel,   dim3(512), dim3(256), 0, stream,
                     OW, WcT, bc, x, gamma, out);
}